// Round 1
// baseline (326.569 us; speedup 1.0000x reference)
//
#include <hip/hip_runtime.h>
#include <math.h>

#define KN 50000
#define KK 64
#define CAP 64

// Fill per-dst bucket CSR (slots/cnt) and detect edges incident to `node`.
__global__ void k_bucket_targets(const int* __restrict__ ei, int E,
                                 const int* __restrict__ nodep,
                                 int* __restrict__ cnt, int* __restrict__ slots,
                                 int* __restrict__ tcount, int* __restrict__ tpairs) {
    int node = nodep[0];
    int stride = gridDim.x * blockDim.x;
    for (int e = blockIdx.x * blockDim.x + threadIdx.x; e < E; e += stride) {
        int s = ei[e];
        int d = ei[E + e];
        int p = atomicAdd(&cnt[d], 1);
        if (p < CAP) slots[(size_t)d * CAP + p] = s;
        if (s == node || d == node) {
            int q = atomicAdd(tcount, 1);
            if (q < KK) { tpairs[2 * q] = e; tpairs[2 * q + 1] = (s == node) ? d : s; }
        }
    }
}

__global__ void k_dinv(const int* __restrict__ cnt, float* __restrict__ dinv, int N) {
    int v = blockIdx.x * blockDim.x + threadIdx.x;
    if (v < N) dinv[v] = rsqrtf((float)(cnt[v] + 1));  // +1 self-loop
}

// y[u,c] = dinv[u] * sum_f in[u,f] * W[f,c]   (16 rows per 256-thread block)
__global__ __launch_bounds__(256) void k_gemm_scale(const float* __restrict__ in,
                                                    const float* __restrict__ W,
                                                    const float* __restrict__ dinv,
                                                    float* __restrict__ y, int N) {
    __shared__ __align__(16) float Ws[64 * 64];
    __shared__ __align__(16) float xs[16 * 64];
    int tid = threadIdx.x;
    int base = blockIdx.x * 16;

    const float4* W4 = (const float4*)W;
    float4* Ws4 = (float4*)Ws;
    for (int i = tid; i < 1024; i += 256) Ws4[i] = W4[i];
    const float4* in4 = (const float4*)(in + (size_t)base * 64);
    ((float4*)xs)[tid] = in4[tid];
    __syncthreads();

    int c = tid & 63;
    int r0 = tid >> 6;  // 0..3
    float a0 = 0.f, a1 = 0.f, a2 = 0.f, a3 = 0.f;
#pragma unroll
    for (int f = 0; f < 64; f++) {
        float w = Ws[f * 64 + c];
        a0 += xs[(r0) * 64 + f] * w;
        a1 += xs[(r0 + 4) * 64 + f] * w;
        a2 += xs[(r0 + 8) * 64 + f] * w;
        a3 += xs[(r0 + 12) * 64 + f] * w;
    }
    int r;
    r = base + r0;      y[(size_t)r * 64 + c] = dinv[r] * a0;
    r = base + r0 + 4;  y[(size_t)r * 64 + c] = dinv[r] * a1;
    r = base + r0 + 8;  y[(size_t)r * 64 + c] = dinv[r] * a2;
    r = base + r0 + 12; y[(size_t)r * 64 + c] = dinv[r] * a3;
}

// out[v,c] = relu(dinv[v] * (y[v,c] + sum_{in-edges} y[src,c]) + b[c])
__global__ __launch_bounds__(256) void k_agg(const float* __restrict__ y,
                                             const int* __restrict__ slots,
                                             const int* __restrict__ cnt,
                                             const float* __restrict__ dinv,
                                             const float* __restrict__ bias,
                                             float* __restrict__ out, int N) {
    int v = blockIdx.x * 4 + (threadIdx.x >> 6);
    int lane = threadIdx.x & 63;
    if (v >= N) return;
    float acc = y[(size_t)v * 64 + lane];  // self-loop term
    int c = cnt[v];
    const int* sl = slots + (size_t)v * CAP;
    for (int i = 0; i < c; i++) {
        int u = sl[i];
        acc += y[(size_t)u * 64 + lane];
    }
    float r = dinv[v] * acc + bias[lane];
    out[(size_t)v * 64 + lane] = fmaxf(r, 0.0f);
}

// Sort the K incident edges by edge index (reference nonzero order), score, softmax.
__global__ void k_score(const float* __restrict__ h2, const int* __restrict__ tpairs,
                        const float* __restrict__ Wr, const float* __restrict__ br,
                        float* __restrict__ out) {
    __shared__ int sidx[KK], stgt[KK], ssort[KK];
    int lane = threadIdx.x;
    sidx[lane] = tpairs[2 * lane];
    stgt[lane] = tpairs[2 * lane + 1];
    __syncthreads();
    int my = sidx[lane];
    int rank = 0;
    for (int j = 0; j < KK; j++) rank += (sidx[j] < my) ? 1 : 0;
    ssort[rank] = stgt[lane];
    __syncthreads();
    int tgt = ssort[lane];
    float acc = br[0];
    for (int cc = 0; cc < 64; cc++) acc += h2[(size_t)tgt * 64 + cc] * Wr[cc];
    // softmax across the 64-lane wave
    float m = acc;
#pragma unroll
    for (int off = 32; off >= 1; off >>= 1) m = fmaxf(m, __shfl_xor(m, off));
    float e = __expf(acc - m);
    float s = e;
#pragma unroll
    for (int off = 32; off >= 1; off >>= 1) s += __shfl_xor(s, off);
    out[lane] = e / s;
    out[64 + lane] = (float)tgt;
}

extern "C" void kernel_launch(void* const* d_in, const int* in_sizes, int n_in,
                              void* d_out, int out_size, void* d_ws, size_t ws_size,
                              hipStream_t stream) {
    const float* x  = (const float*)d_in[0];
    const int*   ei = (const int*)d_in[1];
    const int*   nodep = (const int*)d_in[2];
    const float* W1 = (const float*)d_in[3];
    const float* b1 = (const float*)d_in[4];
    const float* W2 = (const float*)d_in[5];
    const float* b2 = (const float*)d_in[6];
    const float* Wr = (const float*)d_in[7];
    const float* br = (const float*)d_in[8];
    float* out = (float*)d_out;

    int N = in_sizes[0] / 64;   // 50000
    int E = in_sizes[1] / 2;    // 800064

    char* w = (char*)d_ws;
    float* y    = (float*)w; w += (size_t)N * 64 * 4;
    float* h1   = (float*)w; w += (size_t)N * 64 * 4;
    float* h2   = (float*)w; w += (size_t)N * 64 * 4;
    int*   slots= (int*)w;   w += (size_t)N * CAP * 4;
    float* dinv = (float*)w; w += (size_t)N * 4;
    int*   cnt  = (int*)w;   w += (size_t)N * 4;
    int*   tcount = (int*)w; w += 4;
    int*   tpairs = (int*)w; w += 2 * KK * 4;

    // zero cnt + tcount (contiguous) — ws is poisoned 0xAA before every call
    hipMemsetAsync(cnt, 0, ((size_t)N + 1) * sizeof(int), stream);

    k_bucket_targets<<<1024, 256, 0, stream>>>(ei, E, nodep, cnt, slots, tcount, tpairs);
    k_dinv<<<(N + 255) / 256, 256, 0, stream>>>(cnt, dinv, N);

    k_gemm_scale<<<N / 16, 256, 0, stream>>>(x, W1, dinv, y, N);
    k_agg<<<N / 4, 256, 0, stream>>>(y, slots, cnt, dinv, b1, h1, N);

    k_gemm_scale<<<N / 16, 256, 0, stream>>>(h1, W2, dinv, y, N);
    k_agg<<<N / 4, 256, 0, stream>>>(y, slots, cnt, dinv, b2, h2, N);

    k_score<<<1, 64, 0, stream>>>(h2, tpairs, Wr, br, out);
}

// Round 2
// 212.393 us; speedup vs baseline: 1.5376x; 1.5376x over previous
//
#include <hip/hip_runtime.h>
#include <math.h>

#define KK 64
#define CAP 64
#define NF 4160   // 64 targets x (1 self + 64 slot entries)

// Fill per-dst bucket CSR (slots/cnt) and detect edges incident to `node`.
__global__ void k_bucket(const int* __restrict__ ei, int E,
                         const int* __restrict__ nodep,
                         int* __restrict__ cnt, int* __restrict__ slots,
                         int* __restrict__ tcount, int* __restrict__ tpairs) {
    int node = nodep[0];
    int stride = gridDim.x * blockDim.x;
    for (int e = blockIdx.x * blockDim.x + threadIdx.x; e < E; e += stride) {
        int s = ei[e];
        int d = ei[E + e];
        int p = atomicAdd(&cnt[d], 1);
        if (p < CAP) slots[(size_t)d * CAP + p] = s;
        if (s == node || d == node) {
            int q = atomicAdd(tcount, 1);
            if (q < KK) { tpairs[2 * q] = e; tpairs[2 * q + 1] = (s == node) ? d : s; }
        }
    }
}

__global__ void k_dinv(const int* __restrict__ cnt, float* __restrict__ dinv, int N) {
    int v = blockIdx.x * blockDim.x + threadIdx.x;
    if (v < N) dinv[v] = rsqrtf((float)(cnt[v] + 1));  // +1 self-loop
}

// Sort targets by edge index (reference nonzero order); build frontier list:
// frontier[tp*65 + 0] = target, frontier[tp*65 + 1+k] = slots[target][k] or -1.
__global__ void k_frontier(const int* __restrict__ tpairs, const int* __restrict__ cnt,
                           const int* __restrict__ slots,
                           int* __restrict__ frontier, int* __restrict__ tsorted) {
    __shared__ int eidx[KK], tgt[KK], sorted_[KK];
    int tid = threadIdx.x;  // 256 threads
    if (tid < KK) { eidx[tid] = tpairs[2 * tid]; tgt[tid] = tpairs[2 * tid + 1]; }
    __syncthreads();
    if (tid < KK) {
        int my = eidx[tid];
        int rank = 0;
        for (int j = 0; j < KK; j++) rank += (eidx[j] < my) ? 1 : 0;
        sorted_[rank] = tgt[tid];
    }
    __syncthreads();
    if (tid < KK) tsorted[tid] = sorted_[tid];
    for (int i = tid; i < NF; i += 256) {
        int tp = i / 65, j = i % 65;
        int t = sorted_[tp];
        int f;
        if (j == 0) f = t;
        else f = (j - 1 < cnt[t]) ? slots[(size_t)t * CAP + (j - 1)] : -1;
        frontier[i] = f;
    }
}

// Layer-1 aggregation in x-space, selective: zx[i] = d[v]*(d[v]*x[v] + sum d[u]*x[u])
__global__ __launch_bounds__(256) void k_agg1(const float* __restrict__ x,
                                              const int* __restrict__ frontier,
                                              const int* __restrict__ slots,
                                              const int* __restrict__ cnt,
                                              const float* __restrict__ dinv,
                                              float* __restrict__ zx) {
    int i = blockIdx.x * 4 + (threadIdx.x >> 6);
    int lane = threadIdx.x & 63;
    if (i >= NF) return;
    int v = frontier[i];
    if (v < 0) return;
    float dv = dinv[v];
    float acc = dv * x[(size_t)v * 64 + lane];
    int c = cnt[v];
    const int* sl = slots + (size_t)v * CAP;
    int k = 0;
    for (; k + 4 <= c; k += 4) {
        int u0 = sl[k], u1 = sl[k + 1], u2 = sl[k + 2], u3 = sl[k + 3];
        float f0 = dinv[u0], f1 = dinv[u1], f2 = dinv[u2], f3 = dinv[u3];
        float x0 = x[(size_t)u0 * 64 + lane];
        float x1 = x[(size_t)u1 * 64 + lane];
        float x2 = x[(size_t)u2 * 64 + lane];
        float x3 = x[(size_t)u3 * 64 + lane];
        acc += f0 * x0 + f1 * x1 + f2 * x2 + f3 * x3;
    }
    for (; k < c; k++) {
        int u = sl[k];
        acc += dinv[u] * x[(size_t)u * 64 + lane];
    }
    zx[(size_t)i * 64 + lane] = dv * acc;
}

// h1c[i] = relu(zx[i] @ W1 + b1), 16 rows / 256-thread block
__global__ __launch_bounds__(256) void k_gemm_h1(const float* __restrict__ zx,
                                                 const float* __restrict__ W1,
                                                 const float* __restrict__ b1,
                                                 float* __restrict__ h1c) {
    __shared__ __align__(16) float Ws[64 * 64];
    __shared__ __align__(16) float xs[16 * 64];
    int tid = threadIdx.x;
    int base = blockIdx.x * 16;
    for (int i = tid; i < 1024; i += 256) ((float4*)Ws)[i] = ((const float4*)W1)[i];
    ((float4*)xs)[tid] = ((const float4*)(zx + (size_t)base * 64))[tid];
    __syncthreads();
    int c = tid & 63, r0 = tid >> 6;
    float a0 = 0.f, a1 = 0.f, a2 = 0.f, a3 = 0.f;
#pragma unroll
    for (int f = 0; f < 64; f++) {
        float w = Ws[f * 64 + c];
        a0 += xs[r0 * 64 + f] * w;
        a1 += xs[(r0 + 4) * 64 + f] * w;
        a2 += xs[(r0 + 8) * 64 + f] * w;
        a3 += xs[(r0 + 12) * 64 + f] * w;
    }
    float b = b1[c];
    h1c[(size_t)(base + r0) * 64 + c]      = fmaxf(a0 + b, 0.f);
    h1c[(size_t)(base + r0 + 4) * 64 + c]  = fmaxf(a1 + b, 0.f);
    h1c[(size_t)(base + r0 + 8) * 64 + c]  = fmaxf(a2 + b, 0.f);
    h1c[(size_t)(base + r0 + 12) * 64 + c] = fmaxf(a3 + b, 0.f);
}

// Layer-2 + score + softmax for the 64 targets. One block, 16 waves.
__global__ __launch_bounds__(1024) void k_final(const float* __restrict__ h1c,
                                                const int* __restrict__ frontier,
                                                const int* __restrict__ tsorted,
                                                const float* __restrict__ dinv,
                                                const float* __restrict__ W2,
                                                const float* __restrict__ b2,
                                                const float* __restrict__ Wr,
                                                const float* __restrict__ br,
                                                float* __restrict__ out) {
    __shared__ __align__(16) float W2s[64 * 64];
    __shared__ float sc[KK];
    int tid = threadIdx.x;
    for (int i = tid; i < 1024; i += 1024) ((float4*)W2s)[i] = ((const float4*)W2)[i];
    __syncthreads();
    int wave = tid >> 6;   // 0..15
    int lane = tid & 63;
    for (int tp = wave; tp < KK; tp += 16) {
        int t = tsorted[tp];
        float dt = dinv[t];
        // z2 = d[t]*h1[t] + sum_u d[u]*h1[u]  (all rows live compactly in h1c)
        float z = dt * h1c[(size_t)(tp * 65) * 64 + lane];
        for (int j = 1; j < 65; j++) {
            int u = frontier[tp * 65 + j];
            if (u < 0) break;   // contiguous valid prefix
            z += dinv[u] * h1c[(size_t)(tp * 65 + j) * 64 + lane];
        }
        // acc[c] = sum_f z_f * W2[f][c]
        float acc = 0.f;
#pragma unroll
        for (int f = 0; f < 64; f++) {
            float zf = __shfl(z, f);
            acc += zf * W2s[f * 64 + lane];
        }
        float h2 = fmaxf(dt * acc + b2[lane], 0.f);
        float p = h2 * Wr[lane];
#pragma unroll
        for (int off = 32; off >= 1; off >>= 1) p += __shfl_xor(p, off);
        if (lane == 0) sc[tp] = p + br[0];
    }
    __syncthreads();
    if (tid < KK) {
        float s = sc[tid];
        float m = s;
#pragma unroll
        for (int off = 32; off >= 1; off >>= 1) m = fmaxf(m, __shfl_xor(m, off));
        float e = __expf(s - m);
        float ssum = e;
#pragma unroll
        for (int off = 32; off >= 1; off >>= 1) ssum += __shfl_xor(ssum, off);
        out[tid] = e / ssum;
        out[KK + tid] = (float)tsorted[tid];
    }
}

extern "C" void kernel_launch(void* const* d_in, const int* in_sizes, int n_in,
                              void* d_out, int out_size, void* d_ws, size_t ws_size,
                              hipStream_t stream) {
    const float* x  = (const float*)d_in[0];
    const int*   ei = (const int*)d_in[1];
    const int*   nodep = (const int*)d_in[2];
    const float* W1 = (const float*)d_in[3];
    const float* b1 = (const float*)d_in[4];
    const float* W2 = (const float*)d_in[5];
    const float* b2 = (const float*)d_in[6];
    const float* Wr = (const float*)d_in[7];
    const float* br = (const float*)d_in[8];
    float* out = (float*)d_out;

    int N = in_sizes[0] / 64;   // 50000
    int E = in_sizes[1] / 2;    // 800064

    char* w = (char*)d_ws;
    int*   slots    = (int*)w;   w += (size_t)N * CAP * 4;   // 12.8 MB
    int*   cnt      = (int*)w;   w += (size_t)N * 4;
    float* dinv     = (float*)w; w += (size_t)N * 4;
    float* zx       = (float*)w; w += (size_t)NF * 64 * 4;
    float* h1c      = (float*)w; w += (size_t)NF * 64 * 4;
    int*   frontier = (int*)w;   w += (size_t)NF * 4;
    int*   tsorted  = (int*)w;   w += KK * 4;
    int*   tpairs   = (int*)w;   w += 2 * KK * 4;
    int*   tcount   = (int*)w;   w += 16;

    hipMemsetAsync(cnt, 0, (size_t)N * sizeof(int), stream);
    hipMemsetAsync(tcount, 0, sizeof(int), stream);

    int ebl = (E + 255) / 256;
    k_bucket<<<ebl, 256, 0, stream>>>(ei, E, nodep, cnt, slots, tcount, tpairs);
    k_dinv<<<(N + 255) / 256, 256, 0, stream>>>(cnt, dinv, N);
    k_frontier<<<1, 256, 0, stream>>>(tpairs, cnt, slots, frontier, tsorted);
    k_agg1<<<NF / 4, 256, 0, stream>>>(x, frontier, slots, cnt, dinv, zx);
    k_gemm_h1<<<NF / 16, 256, 0, stream>>>(zx, W1, b1, h1c);
    k_final<<<1, 1024, 0, stream>>>(h1c, frontier, tsorted, dinv, W2, b2, Wr, br, out);
}